// Round 13
// baseline (104.409 us; speedup 1.0000x reference)
//
#include <hip/hip_runtime.h>
#include <hip/hip_bf16.h>

// GatingNetwork: h = x@fc_w^T + b; BatchNorm(batch axis); ReLU;
// capsule u = h @ W_caps[e]; squash; 3-iter dynamic routing; logits; softmax.
// B=131072, D_IN=HID=256, E=4, CAP=16.
//
// 3-kernel pipeline:
//  k_prep: fc_w -> bf16 hi/lo planes (BK=32 groups, slot-permuted) + zero stats
//  k_gemm: 2-product bf16 MFMA with COUNTED-vmcnt pipeline (raw s_barrier,
//          never vmcnt(0) in the loop): x(k+1) regs + self-owned B-DMA(k+1)
//          stay in flight across barriers. h stored bf16.
//  k_fuse: BN-finalize + ReLU + MFMA capsules (3-product) + routing

#define BATCH   131072
#define INV_B   (1.0f / 131072.0f)

typedef __attribute__((ext_vector_type(8))) short  short8;   // 8 bf16 (4 VGPR)
typedef __attribute__((ext_vector_type(4))) float  f32x4;

__device__ __forceinline__ unsigned bf16_rn(float f) {
    unsigned u = __float_as_uint(f);
    return (u + 0x7fffu + ((u >> 16) & 1u)) >> 16;
}

__device__ __forceinline__ void split8(const float* v, uint4& hi, uint4& lo) {
    unsigned hb[8], lb[8];
#pragma unroll
    for (int j = 0; j < 8; ++j) {
        union { __hip_bfloat16 b; ushort u; } ch, cl;
        ch.b = __float2bfloat16(v[j]);
        float res = v[j] - __bfloat162float(ch.b);
        cl.b = __float2bfloat16(res);
        hb[j] = ch.u;
        lb[j] = cl.u;
    }
    hi = make_uint4(hb[0] | (hb[1] << 16), hb[2] | (hb[3] << 16),
                    hb[4] | (hb[5] << 16), hb[6] | (hb[7] << 16));
    lo = make_uint4(lb[0] | (lb[1] << 16), lb[2] | (lb[3] << 16),
                    lb[4] | (lb[5] << 16), lb[6] | (lb[7] << 16));
}

// pack 8 fp32 -> 8 bf16 (RN), hi only
__device__ __forceinline__ uint4 cvt8(const float* v) {
    unsigned hb[8];
#pragma unroll
    for (int j = 0; j < 8; ++j) {
        union { __hip_bfloat16 b; ushort u; } ch;
        ch.b = __float2bfloat16(v[j]);
        hb[j] = ch.u;
    }
    return make_uint4(hb[0] | (hb[1] << 16), hb[2] | (hb[3] << 16),
                      hb[4] | (hb[5] << 16), hb[6] | (hb[7] << 16));
}

// ---------------------------------------------------------------------------
// Kernel 0: split fc_w into bf16 hi/lo planes grouped by BK=32 K-step, chunk
// permutation slot = (c + (j>>1)) & 3 pre-applied. Block 0 zeroes stats.
// ---------------------------------------------------------------------------
__global__ void k_prep(const float* __restrict__ w, ushort* __restrict__ wsp,
                       float* __restrict__ gsum, float* __restrict__ gsq)
{
    if (blockIdx.x == 0) { gsum[threadIdx.x] = 0.f; gsq[threadIdx.x] = 0.f; }
    const int cid = (int)blockIdx.x * 256 + threadIdx.x;  // 0..8191 chunks of 8
    const int j   = cid >> 5;          // output col 0..255
    const int ks  = (cid >> 2) & 7;    // K-step 0..7
    const int c   = cid & 3;           // 8-elem chunk within 32
    const float* wp = w + j * 256 + ks * 32 + c * 8;
    float4 v0 = *(const float4*)(wp);
    float4 v1 = *(const float4*)(wp + 4);
    float va[8] = {v0.x, v0.y, v0.z, v0.w, v1.x, v1.y, v1.z, v1.w};
    uint4 hi, lo;
    split8(va, hi, lo);
    const int slot = (c + (j >> 1)) & 3;
    *(uint4*)&wsp[ks * 8192 + j * 32 + slot * 8]         = hi;
    *(uint4*)&wsp[65536 + ks * 8192 + j * 32 + slot * 8] = lo;
}

// ---------------------------------------------------------------------------
// Kernel 1: 2-product bf16 MFMA GEMM, counted-vmcnt pipeline.
// BM=128, BN=128, BK=32, 256 thr = 4 waves (2M x 2N), 64x64 per wave.
// Per step k: issue x(k+1) (4 vmem) then SELF-OWNED B-DMA(k+1) (8 gload_lds,
// each wave stages exactly the 4KB/plane it reads; sharing waves stage
// redundantly byte-identical). vmcnt(12) -> B(k) landed. frags+MFMA.
// vmcnt(8) -> x(k+1) landed (B(k+1) still in flight). cvt+ds_write A[alt].
// lgkmcnt(0) + RAW s_barrier (no vmem drain!).
// ---------------------------------------------------------------------------
__global__ __launch_bounds__(256, 3) void k_gemm(
    const float* __restrict__ x, const ushort* __restrict__ wsp,
    const float* __restrict__ bias, ushort* __restrict__ h,
    float* __restrict__ gsum, float* __restrict__ gsq)
{
    __shared__ ushort Ah[2][128 * 32];     // 16KB
    __shared__ ushort Bhs[2][128 * 32];    // 16KB
    __shared__ ushort Bls[2][128 * 32];    // 16KB
    __shared__ float  csum[128];
    __shared__ float  csq[128];

    const int t   = threadIdx.x;
    const int wid = t >> 6;            // 0..3
    const int l   = t & 63;
    const int wm  = wid >> 1;          // 0..1 (64-row slab)
    const int wn  = wid & 1;           // 0..1 (64-col slab)
    const int g   = l >> 4;            // k-quarter (chunk of 8)
    const int lc  = l & 15;

    const int wg = ((int)blockIdx.x & 7) * 256 + ((int)blockIdx.x >> 3);
    const int bm = (wg >> 1) * 128;
    const int bn = (wg & 1) * 128;

    if (t < 128) { csum[t] = 0.f; csq[t] = 0.f; }

    f32x4 acc[4][4];
#pragma unroll
    for (int mi = 0; mi < 4; ++mi)
#pragma unroll
        for (int ni = 0; ni < 4; ++ni)
            acc[mi][ni] = (f32x4){0.f, 0.f, 0.f, 0.f};

    float bb[4];
#pragma unroll
    for (int ni = 0; ni < 4; ++ni)
        bb[ni] = bias[bn + wn * 64 + ni * 16 + lc];

    // A staging geometry: thread t -> row ar, chunks c0,c0+1 (64B of x)
    const int ar  = t >> 1;
    const int ac0 = (t & 1) * 2;
    const int as0 = (ac0 + (ar >> 1)) & 3;
    const int as1 = (ac0 + 1 + (ar >> 1)) & 3;
    const float* aptr = x + (size_t)(bm + ar) * 256 + ac0 * 8;

    // B self-staging: wave stages the 4KB/plane (64 cols) it reads.
    // global src cols: bn + wn*64 .. +63 -> ushort off ks*8192 + (bn+wn*64)*32
    // LDS dst bytes: wn*4096 + i*1024
    const size_t bsrc0 = (size_t)(bn + wn * 64) * 32;   // ushort offset base

#define STAGE_B(KS, BUF)                                                      \
    {                                                                         \
        const char* sh_ = (const char*)(wsp + (KS) * 8192 + bsrc0);           \
        const char* sl_ = (const char*)(wsp + 65536 + (KS) * 8192 + bsrc0);   \
        char* dh_ = (char*)Bhs[BUF] + wn * 4096;                              \
        char* dl_ = (char*)Bls[BUF] + wn * 4096;                              \
        _Pragma("unroll")                                                     \
        for (int i_ = 0; i_ < 4; ++i_) {                                      \
            __builtin_amdgcn_global_load_lds(                                 \
                (const __attribute__((address_space(1))) unsigned*)(sh_ + i_ * 1024 + l * 16), \
                (__attribute__((address_space(3))) unsigned*)(dh_ + i_ * 1024), 16, 0, 0); \
            __builtin_amdgcn_global_load_lds(                                 \
                (const __attribute__((address_space(1))) unsigned*)(sl_ + i_ * 1024 + l * 16), \
                (__attribute__((address_space(3))) unsigned*)(dl_ + i_ * 1024), 16, 0, 0); \
        }                                                                     \
    }

    // ---- prologue: x(0)->regs, B(0)->buf0, drain all, A(0) write, barrier --
    float4 v0 = *(const float4*)(aptr);
    float4 v1 = *(const float4*)(aptr + 4);
    float4 v2 = *(const float4*)(aptr + 8);
    float4 v3 = *(const float4*)(aptr + 12);
    STAGE_B(0, 0)
    asm volatile("s_waitcnt vmcnt(0)" ::: "memory");
    {
        float va[8] = {v0.x, v0.y, v0.z, v0.w, v1.x, v1.y, v1.z, v1.w};
        float vb[8] = {v2.x, v2.y, v2.z, v2.w, v3.x, v3.y, v3.z, v3.w};
        *(uint4*)&Ah[0][ar * 32 + as0 * 8] = cvt8(va);
        *(uint4*)&Ah[0][ar * 32 + as1 * 8] = cvt8(vb);
    }
    asm volatile("s_waitcnt lgkmcnt(0)" ::: "memory");
    __builtin_amdgcn_s_barrier();

    int cur = 0;
#pragma unroll 1
    for (int ks = 0; ks < 8; ++ks) {
        // ---- issue next step's loads (stay in flight across the barrier) --
        if (ks < 7) {
            const float* ap = aptr + (ks + 1) * 32;
            v0 = *(const float4*)(ap);
            v1 = *(const float4*)(ap + 4);
            v2 = *(const float4*)(ap + 8);
            v3 = *(const float4*)(ap + 12);
            STAGE_B(ks + 1, cur ^ 1)
            // B(k) landed (oldest 8 of [B(k)8, x4, B(k+1)8] drained)
            asm volatile("s_waitcnt vmcnt(12)" ::: "memory");
        } else {
            asm volatile("s_waitcnt vmcnt(0)" ::: "memory");
        }
        __builtin_amdgcn_sched_barrier(0);

        // ---- frags + 32 MFMA on A[cur], B[cur] ----
        {
            short8 ahf[4];
#pragma unroll
            for (int mi = 0; mi < 4; ++mi) {
                const int row = wm * 64 + mi * 16 + lc;
                const int off = row * 32 + ((g + (row >> 1)) & 3) * 8;
                ahf[mi] = *(const short8*)&Ah[cur][off];
            }
#pragma unroll
            for (int ni = 0; ni < 4; ++ni) {
                const int col = wn * 64 + ni * 16 + lc;
                const int off = col * 32 + ((g + (col >> 1)) & 3) * 8;
                short8 bhf = *(const short8*)&Bhs[cur][off];
                short8 blf = *(const short8*)&Bls[cur][off];
#pragma unroll
                for (int mi = 0; mi < 4; ++mi) {
                    acc[mi][ni] = __builtin_amdgcn_mfma_f32_16x16x32_bf16(
                        ahf[mi], bhf, acc[mi][ni], 0, 0, 0);
                    acc[mi][ni] = __builtin_amdgcn_mfma_f32_16x16x32_bf16(
                        ahf[mi], blf, acc[mi][ni], 0, 0, 0);
                }
            }
        }

        if (ks < 7) {
            // x(k+1) landed; B(k+1) (newest 8) may still be in flight
            asm volatile("s_waitcnt vmcnt(8)" ::: "memory");
            __builtin_amdgcn_sched_barrier(0);
            float va[8] = {v0.x, v0.y, v0.z, v0.w, v1.x, v1.y, v1.z, v1.w};
            float vb[8] = {v2.x, v2.y, v2.z, v2.w, v3.x, v3.y, v3.z, v3.w};
            *(uint4*)&Ah[cur ^ 1][ar * 32 + as0 * 8] = cvt8(va);
            *(uint4*)&Ah[cur ^ 1][ar * 32 + as1 * 8] = cvt8(vb);
            // own ds_writes done -> raw barrier (NO vmem drain)
            asm volatile("s_waitcnt lgkmcnt(0)" ::: "memory");
            __builtin_amdgcn_s_barrier();
        }
        cur ^= 1;
    }
#undef STAGE_B

    // ---- epilogue: bias add, quantize h to bf16, store, stats ----
    float lsum[4] = {0.f, 0.f, 0.f, 0.f};
    float lsq[4]  = {0.f, 0.f, 0.f, 0.f};

#pragma unroll
    for (int mi = 0; mi < 4; ++mi)
#pragma unroll
        for (int ni = 0; ni < 4; ++ni) {
            const int colg = bn + wn * 64 + ni * 16 + lc;
#pragma unroll
            for (int reg = 0; reg < 4; ++reg) {
                const int row = bm + wm * 64 + mi * 16 + g * 4 + reg;
                float hv = acc[mi][ni][reg] + bb[ni];
                unsigned hb = bf16_rn(hv);
                float hq = __uint_as_float(hb << 16);
                h[(size_t)row * 256 + colg] = (ushort)hb;
                lsum[ni] += hq;
                lsq[ni]   = fmaf(hq, hq, lsq[ni]);
            }
        }

#pragma unroll
    for (int ni = 0; ni < 4; ++ni) {
        lsum[ni] += __shfl_xor(lsum[ni], 16);
        lsum[ni] += __shfl_xor(lsum[ni], 32);
        lsq[ni]  += __shfl_xor(lsq[ni], 16);
        lsq[ni]  += __shfl_xor(lsq[ni], 32);
    }
    if (l < 16) {
#pragma unroll
        for (int ni = 0; ni < 4; ++ni) {
            atomicAdd(&csum[wn * 64 + ni * 16 + lc], lsum[ni]);
            atomicAdd(&csq[wn * 64 + ni * 16 + lc],  lsq[ni]);
        }
    }
    __syncthreads();
    if (t < 128) {
        atomicAdd(&gsum[bn + t], csum[t]);
        atomicAdd(&gsq[bn + t],  csq[t]);
    }
}

// ---------------------------------------------------------------------------
// Kernel 2: BN-finalize (inline stats) + ReLU + MFMA capsule projection +
// collinear scalar routing. h input is bf16. (verified R12)
// ---------------------------------------------------------------------------
__global__ __launch_bounds__(256) void k_fuse(
    const ushort* __restrict__ h,
    const float* __restrict__ gsum, const float* __restrict__ gsq,
    const float* __restrict__ gamma, const float* __restrict__ beta,
    const float* __restrict__ wc, const float* __restrict__ ow_g,
    const float* __restrict__ ob_g, float* __restrict__ out)
{
    __shared__ ushort Hh[32 * 256];   // 16KB
    __shared__ ushort Hl[32 * 256];   // 16KB
    __shared__ float  us[64 * 68];    // 17KB
    __shared__ float  ows[64];
    __shared__ float  abs_[512];      // scale | shift

    const int t   = threadIdx.x;
    const int wid = t >> 6;
    const int l   = t & 63;
    const int g   = l >> 4;           // 0..3
    const int lc  = l & 15;

    {
        float mean = gsum[t] * INV_B;
        float var  = gsq[t] * INV_B - mean * mean;
        float rstd = rsqrtf(var + 1e-5f);
        float a = gamma[t] * rstd;
        abs_[t]       = a;
        abs_[256 + t] = beta[t] - mean * a;
    }
    if (t < 64) ows[t] = ow_g[t];

    short8 afh[8], afl[8];
#pragma unroll
    for (int ks = 0; ks < 8; ++ks) {
        union { ushort u16[8]; short8 v; } ph, pl;
#pragma unroll
        for (int j = 0; j < 8; ++j) {
            const int d = ks * 32 + g * 8 + j;
            float wv = wc[wid * 4096 + d * 16 + lc];
            unsigned hh = bf16_rn(wv);
            float res = wv - __uint_as_float(hh << 16);
            ph.u16[j] = (ushort)hh;
            pl.u16[j] = (ushort)bf16_rn(res);
        }
        afh[ks] = ph.v;
        afl[ks] = pl.v;
    }
    __syncthreads();   // abs_ ready

    const int c8 = (t & 31) * 8;      // staging column group
    float a_[8], cj[8];
    {
        float4 x0 = *(const float4*)(abs_ + c8);
        float4 x1 = *(const float4*)(abs_ + c8 + 4);
        float4 y0 = *(const float4*)(abs_ + 256 + c8);
        float4 y1 = *(const float4*)(abs_ + 256 + c8 + 4);
        a_[0]=x0.x; a_[1]=x0.y; a_[2]=x0.z; a_[3]=x0.w;
        a_[4]=x1.x; a_[5]=x1.y; a_[6]=x1.z; a_[7]=x1.w;
        cj[0]=y0.x; cj[1]=y0.y; cj[2]=y0.z; cj[3]=y0.w;
        cj[4]=y1.x; cj[5]=y1.y; cj[6]=y1.z; cj[7]=y1.w;
    }

    const int rowBase = (int)blockIdx.x * 64;

#pragma unroll
    for (int sub = 0; sub < 2; ++sub) {
        const int row0 = rowBase + sub * 32;

        __syncthreads();

#pragma unroll
        for (int it = 0; it < 4; ++it) {
            const int r = it * 8 + (t >> 5);          // 0..31
            const ushort* hp = h + (size_t)(row0 + r) * 256 + c8;
            short8 hraw = *(const short8*)hp;         // 16B of bf16
            float hv[8];
#pragma unroll
            for (int j = 0; j < 8; ++j) {
                unsigned ub = (unsigned)(ushort)hraw[j];
                hv[j] = __uint_as_float(ub << 16);
                hv[j] = fmaxf(fmaf(hv[j], a_[j], cj[j]), 0.f);
            }
            uint4 hi, lo;
            split8(hv, hi, lo);
            const int slot = (t & 31) ^ (r & 7);
            *(uint4*)&Hh[r * 256 + slot * 8] = hi;
            *(uint4*)&Hl[r * 256 + slot * 8] = lo;
        }
        __syncthreads();

        f32x4 acc0 = (f32x4){0.f,0.f,0.f,0.f};
        f32x4 acc1 = (f32x4){0.f,0.f,0.f,0.f};
#pragma unroll
        for (int ks = 0; ks < 8; ++ks) {
            {
                const int row  = lc;                   // nt = 0
                const int slot = (ks * 4 + g) ^ (row & 7);
                short8 bh = *(const short8*)&Hh[row * 256 + slot * 8];
                short8 bl = *(const short8*)&Hl[row * 256 + slot * 8];
                acc0 = __builtin_amdgcn_mfma_f32_16x16x32_bf16(afh[ks], bh, acc0, 0,0,0);
                acc0 = __builtin_amdgcn_mfma_f32_16x16x32_bf16(afh[ks], bl, acc0, 0,0,0);
                acc0 = __builtin_amdgcn_mfma_f32_16x16x32_bf16(afl[ks], bh, acc0, 0,0,0);
            }
            {
                const int row  = 16 + lc;              // nt = 1
                const int slot = (ks * 4 + g) ^ (row & 7);
                short8 bh = *(const short8*)&Hh[row * 256 + slot * 8];
                short8 bl = *(const short8*)&Hl[row * 256 + slot * 8];
                acc1 = __builtin_amdgcn_mfma_f32_16x16x32_bf16(afh[ks], bh, acc1, 0,0,0);
                acc1 = __builtin_amdgcn_mfma_f32_16x16x32_bf16(afh[ks], bl, acc1, 0,0,0);
                acc1 = __builtin_amdgcn_mfma_f32_16x16x32_bf16(afl[ks], bh, acc1, 0,0,0);
            }
        }
        {
            const int r0 = sub * 32 + lc;
            *(float4*)&us[r0 * 68 + wid * 16 + g * 4] =
                make_float4(acc0[0], acc0[1], acc0[2], acc0[3]);
            *(float4*)&us[(r0 + 16) * 68 + wid * 16 + g * 4] =
                make_float4(acc1[0], acc1[1], acc1[2], acc1[3]);
        }
    }
    __syncthreads();

    const int row_l = wid * 16 + lc;
    float u[16];
#pragma unroll
    for (int q = 0; q < 4; ++q) {
        float4 v4 = *(const float4*)&us[row_l * 68 + g * 16 + q * 4];
        u[q*4+0] = v4.x; u[q*4+1] = v4.y; u[q*4+2] = v4.z; u[q*4+3] = v4.w;
    }

    float n2 = 0.f;
#pragma unroll
    for (int o = 0; o < 16; ++o) n2 = fmaf(u[o], u[o], n2);
    const float nrm = sqrtf(n2);
    const float sc  = nrm / ((1.f + n2) * (nrm + 1e-8f));  // u_hat = sc*u
    const float nh2 = sc * sc * n2;
    const float nh  = sc * nrm;

    float tk[4];
#pragma unroll
    for (int k = 0; k < 4; ++k) {
        float s = 0.f;
#pragma unroll
        for (int q = 0; q < 4; ++q) {
            float4 w4 = *(const float4*)&ows[k * 16 + q * 4];
            s = fmaf(u[q*4+0], w4.x, s);
            s = fmaf(u[q*4+1], w4.y, s);
            s = fmaf(u[q*4+2], w4.z, s);
            s = fmaf(u[q*4+3], w4.w, s);
        }
        tk[k] = s;
    }

    float b = 0.f, alc = 0.f;
#pragma unroll
    for (int it3 = 0; it3 < 3; ++it3) {
        float bmax = fmaxf(b, __shfl_xor(b, 16));
        bmax = fmaxf(bmax, __shfl_xor(bmax, 32));
        float eb = __expf(b - bmax);
        float es = eb + __shfl_xor(eb, 16);
        es += __shfl_xor(es, 32);
        float c = eb / es;
        float ns  = c * nh;
        float ns2 = c * c * nh2;
        float av  = ns / ((1.f + ns2) * (ns + 1e-8f));
        alc = av * c;
        if (it3 < 2) b += alc * nh2;
    }

    const float vs = alc * sc;
    float p0 = fmaf(vs, tk[0], ob_g[0]);
    float p1 = fmaf(vs, tk[1], ob_g[1]);
    float p2 = fmaf(vs, tk[2], ob_g[2]);
    float p3 = fmaf(vs, tk[3], ob_g[3]);
    float mx = fmaxf(fmaxf(p0, p1), fmaxf(p2, p3));
    float e0 = __expf(p0 - mx), e1 = __expf(p1 - mx);
    float e2 = __expf(p2 - mx), e3 = __expf(p3 - mx);
    float inv = 1.f / (e0 + e1 + e2 + e3);
    *(float4*)&out[(size_t)(rowBase + row_l) * 16 + g * 4] =
        make_float4(e0 * inv, e1 * inv, e2 * inv, e3 * inv);
}

// ---------------------------------------------------------------------------
extern "C" void kernel_launch(void* const* d_in, const int* in_sizes, int n_in,
                              void* d_out, int out_size, void* d_ws, size_t ws_size,
                              hipStream_t stream)
{
    const float* x     = (const float*)d_in[0];
    const float* fc_w  = (const float*)d_in[1];
    const float* fc_b  = (const float*)d_in[2];
    const float* gamma = (const float*)d_in[3];
    const float* beta  = (const float*)d_in[4];
    const float* wc    = (const float*)d_in[5];
    const float* ow    = (const float*)d_in[6];
    const float* ob    = (const float*)d_in[7];
    float* out = (float*)d_out;

    float*  gsum = (float*)d_ws;                  // [256]
    float*  gsq  = gsum + 256;                    // [256]
    ushort* h    = (ushort*)((char*)d_ws + 4096); // [131072*256] bf16 = 67MB

    // w-split planes live in d_out's first 256KB: written by k_prep, read by
    // k_gemm (L2-resident), then fully overwritten by k_fuse's output (8MB).
    ushort* wsp = (ushort*)d_out;                 // hi|lo planes, BK=32 layout

    k_prep <<<dim3(32),   dim3(256), 0, stream>>>(fc_w, wsp, gsum, gsq);
    k_gemm <<<dim3(2048), dim3(256), 0, stream>>>(x, wsp, fc_b, h, gsum, gsq);
    k_fuse <<<dim3(2048), dim3(256), 0, stream>>>(h, gsum, gsq, gamma, beta,
                                                  wc, ow, ob, out);
}

// Round 14
// 89.169 us; speedup vs baseline: 1.1709x; 1.1709x over previous
//
#include <hip/hip_runtime.h>
#include <hip/hip_bf16.h>

// GatingNetwork: h = x@fc_w^T + b; BatchNorm(batch axis); ReLU;
// capsule u = h @ W_caps[e]; squash; 3-iter dynamic routing; logits; softmax.
// B=131072, D_IN=HID=256, E=4, CAP=16.
//
// 3-kernel pipeline:
//  k_prep: fc_w -> bf16 hi/lo planes (BK=32 groups, slot-permuted) + zero stats
//  k_gemm: 2-product bf16 MFMA; ALL memory paths segment-optimal:
//          A loads 8rows x 128B contiguous per instr, B staged cooperatively
//          (no redundancy), epilogue via LDS transpose -> full-line stores.
//  k_fuse: BN-finalize + ReLU + MFMA capsules (3-product) + routing

#define BATCH   131072
#define INV_B   (1.0f / 131072.0f)

typedef __attribute__((ext_vector_type(8))) short  short8;   // 8 bf16 (4 VGPR)
typedef __attribute__((ext_vector_type(4))) float  f32x4;

__device__ __forceinline__ unsigned bf16_rn(float f) {
    unsigned u = __float_as_uint(f);
    return (u + 0x7fffu + ((u >> 16) & 1u)) >> 16;
}

__device__ __forceinline__ unsigned pack2bf(float a, float b) {
    union { __hip_bfloat16 b; ushort u; } ca, cb;
    ca.b = __float2bfloat16(a);
    cb.b = __float2bfloat16(b);
    return (unsigned)ca.u | ((unsigned)cb.u << 16);
}

__device__ __forceinline__ void split8(const float* v, uint4& hi, uint4& lo) {
    unsigned hb[8], lb[8];
#pragma unroll
    for (int j = 0; j < 8; ++j) {
        union { __hip_bfloat16 b; ushort u; } ch, cl;
        ch.b = __float2bfloat16(v[j]);
        float res = v[j] - __bfloat162float(ch.b);
        cl.b = __float2bfloat16(res);
        hb[j] = ch.u;
        lb[j] = cl.u;
    }
    hi = make_uint4(hb[0] | (hb[1] << 16), hb[2] | (hb[3] << 16),
                    hb[4] | (hb[5] << 16), hb[6] | (hb[7] << 16));
    lo = make_uint4(lb[0] | (lb[1] << 16), lb[2] | (lb[3] << 16),
                    lb[4] | (lb[5] << 16), lb[6] | (lb[7] << 16));
}

// ---------------------------------------------------------------------------
// Kernel 0: split fc_w into bf16 hi/lo planes grouped by BK=32 K-step, chunk
// permutation slot = (c + (j>>1)) & 3 pre-applied. Block 0 zeroes stats.
// ---------------------------------------------------------------------------
__global__ void k_prep(const float* __restrict__ w, ushort* __restrict__ wsp,
                       float* __restrict__ gsum, float* __restrict__ gsq)
{
    if (blockIdx.x == 0) { gsum[threadIdx.x] = 0.f; gsq[threadIdx.x] = 0.f; }
    const int cid = (int)blockIdx.x * 256 + threadIdx.x;  // 0..8191 chunks of 8
    const int j   = cid >> 5;          // output col 0..255
    const int ks  = (cid >> 2) & 7;    // K-step 0..7
    const int c   = cid & 3;           // 8-elem chunk within 32
    const float* wp = w + j * 256 + ks * 32 + c * 8;
    float4 v0 = *(const float4*)(wp);
    float4 v1 = *(const float4*)(wp + 4);
    float va[8] = {v0.x, v0.y, v0.z, v0.w, v1.x, v1.y, v1.z, v1.w};
    uint4 hi, lo;
    split8(va, hi, lo);
    const int slot = (c + (j >> 1)) & 3;
    *(uint4*)&wsp[ks * 8192 + j * 32 + slot * 8]         = hi;
    *(uint4*)&wsp[65536 + ks * 8192 + j * 32 + slot * 8] = lo;
}

// ---------------------------------------------------------------------------
// Kernel 1: 2-product bf16 MFMA GEMM, transaction-optimal memory paths.
//   h[b,j] ~= sum_d bf16(x[b,d])*w[j,d] + bias[j]   (h stored bf16)
// BM=128, BN=128, BK=32, 256 thr = 4 waves (2M x 2N), 64x64 per wave.
// LDS pool (33.8KB, reused): staging {Ah|Bh|Bl} 24KB; epilogue HT[128][132].
// A: per instr 8 rows x 128B contiguous (16 lines, optimal).
// B: cooperative gload_lds, wave w owns a distinct 4KB quarter (no redund).
// Epilogue: acc -> HT -> coalesced full-line 16B stores.
// ---------------------------------------------------------------------------
__global__ __launch_bounds__(256, 4) void k_gemm(
    const float* __restrict__ x, const ushort* __restrict__ wsp,
    const float* __restrict__ bias, ushort* __restrict__ h,
    float* __restrict__ gsum, float* __restrict__ gsq)
{
    __shared__ ushort POOL[16896];   // 33792B: Ah[0..4095] Bh[4096..] Bl[8192..]
    __shared__ float  csum[128];     // ; epilogue: HT[128][132] over whole pool
    __shared__ float  csq[128];

    const int t   = threadIdx.x;
    const int wid = t >> 6;            // 0..3
    const int l   = t & 63;
    const int wm  = wid >> 1;          // 0..1 (64-row slab)
    const int wn  = wid & 1;           // 0..1 (64-col slab)
    const int g   = l >> 4;            // k-quarter (chunk of 8)
    const int lc  = l & 15;

    // XCD-aware swizzle (2048 % 8 == 0 -> bijective)
    const int wg = ((int)blockIdx.x & 7) * 256 + ((int)blockIdx.x >> 3);
    const int bm = (wg >> 1) * 128;
    const int bn = (wg & 1) * 128;

    if (t < 128) { csum[t] = 0.f; csq[t] = 0.f; }

    f32x4 acc[4][4];
#pragma unroll
    for (int mi = 0; mi < 4; ++mi)
#pragma unroll
        for (int ni = 0; ni < 4; ++ni)
            acc[mi][ni] = (f32x4){0.f, 0.f, 0.f, 0.f};

    float bb[4];
#pragma unroll
    for (int ni = 0; ni < 4; ++ni)
        bb[ni] = bias[bn + wn * 64 + ni * 16 + lc];

    // A staging: round p, thread t -> 16B at tile-linear slot p*256+t
    const int arow = t >> 3;           // within-round row 0..31
    const int ac8  = t & 7;            // 16B chunk within 128B row-step
    const int acp  = ac8 >> 1;         // 16B LDS chunk 0..3
    const int ahf  = ac8 & 1;          // 8B half

    // B staging: wave (isLo, halfsel) owns a distinct 4KB quarter
    const int isLo    = wid >> 1;      // 0: Bh plane, 1: Bl plane
    const int halfsel = wid & 1;       // which 4KB half of the 8KB plane

#pragma unroll 1
    for (int ks = 0; ks < 8; ++ks) {
        __syncthreads();   // previous step's frag readers done

        // ---- B: cooperative async DMA, 4 x 1KB per wave, no redundancy ----
        {
            const char* src = (const char*)(wsp + isLo * 65536 + ks * 8192
                                            + bn * 32 + halfsel * 2048);
            char* dst = (char*)&POOL[4096 + isLo * 4096 + halfsel * 2048];
#pragma unroll
            for (int i = 0; i < 4; ++i) {
                __builtin_amdgcn_global_load_lds(
                    (const __attribute__((address_space(1))) unsigned*)(src + i * 1024 + l * 16),
                    (__attribute__((address_space(3))) unsigned*)(dst + i * 1024),
                    16, 0, 0);
            }
        }

        // ---- A: segment-optimal loads (8 rows x 128B per instr) ----
#pragma unroll
        for (int p = 0; p < 4; ++p) {
            const int r = p * 32 + arow;
            const float* ap = x + (size_t)(bm + r) * 256 + ks * 32 + ac8 * 4;
            float4 v = *(const float4*)ap;
            uint2 pk;
            pk.x = pack2bf(v.x, v.y);
            pk.y = pack2bf(v.z, v.w);
            const int s = (acp + (r >> 1)) & 3;
            *(uint2*)&POOL[r * 32 + s * 8 + ahf * 4] = pk;
        }
        __syncthreads();   // drains gload_lds + ds_writes

        // ---- frags + 32 MFMA ----
        short8 ahfrag[4];
#pragma unroll
        for (int mi = 0; mi < 4; ++mi) {
            const int row = wm * 64 + mi * 16 + lc;
            const int off = row * 32 + ((g + (row >> 1)) & 3) * 8;
            ahfrag[mi] = *(const short8*)&POOL[off];
        }
#pragma unroll
        for (int ni = 0; ni < 4; ++ni) {
            const int col = wn * 64 + ni * 16 + lc;
            const int off = col * 32 + ((g + (col >> 1)) & 3) * 8;
            short8 bhf = *(const short8*)&POOL[4096 + off];
            short8 blf = *(const short8*)&POOL[8192 + off];
#pragma unroll
            for (int mi = 0; mi < 4; ++mi) {
                acc[mi][ni] = __builtin_amdgcn_mfma_f32_16x16x32_bf16(
                    ahfrag[mi], bhf, acc[mi][ni], 0, 0, 0);
                acc[mi][ni] = __builtin_amdgcn_mfma_f32_16x16x32_bf16(
                    ahfrag[mi], blf, acc[mi][ni], 0, 0, 0);
            }
        }
    }

    // ---- epilogue: acc -> HT (LDS, padded 132) + stats, then coalesced ----
    __syncthreads();   // staging buffers dead; POOL becomes HT[128][132]

    float lsum[4] = {0.f, 0.f, 0.f, 0.f};
    float lsq[4]  = {0.f, 0.f, 0.f, 0.f};

#pragma unroll
    for (int mi = 0; mi < 4; ++mi)
#pragma unroll
        for (int ni = 0; ni < 4; ++ni) {
            const int colL = wn * 64 + ni * 16 + lc;
#pragma unroll
            for (int reg = 0; reg < 4; ++reg) {
                const int rowL = wm * 64 + mi * 16 + g * 4 + reg;
                float hv = acc[mi][ni][reg] + bb[ni];
                unsigned hb = bf16_rn(hv);
                float hq = __uint_as_float(hb << 16);
                POOL[rowL * 132 + colL] = (ushort)hb;
                lsum[ni] += hq;
                lsq[ni]   = fmaf(hq, hq, lsq[ni]);
            }
        }
    __syncthreads();

    // coalesced write-out: round p, thread t -> 16B at tile-linear p*256+t
#pragma unroll
    for (int p = 0; p < 8; ++p) {
        const int r   = p * 16 + (t >> 4);
        const int c16 = t & 15;
        short8 vv = *(const short8*)&POOL[r * 132 + c16 * 8];
        *(short8*)(h + (size_t)(bm + r) * 256 + bn + c16 * 8) = vv;
    }

    // stats reduction (unchanged)
#pragma unroll
    for (int ni = 0; ni < 4; ++ni) {
        lsum[ni] += __shfl_xor(lsum[ni], 16);
        lsum[ni] += __shfl_xor(lsum[ni], 32);
        lsq[ni]  += __shfl_xor(lsq[ni], 16);
        lsq[ni]  += __shfl_xor(lsq[ni], 32);
    }
    if (l < 16) {
#pragma unroll
        for (int ni = 0; ni < 4; ++ni) {
            atomicAdd(&csum[wn * 64 + ni * 16 + lc], lsum[ni]);
            atomicAdd(&csq[wn * 64 + ni * 16 + lc],  lsq[ni]);
        }
    }
    __syncthreads();
    if (t < 128) {
        atomicAdd(&gsum[bn + t], csum[t]);
        atomicAdd(&gsq[bn + t],  csq[t]);
    }
}

// ---------------------------------------------------------------------------
// Kernel 2: BN-finalize (inline stats) + ReLU + MFMA capsule projection +
// collinear scalar routing. h input is bf16. (verified R12/R13)
// ---------------------------------------------------------------------------
__global__ __launch_bounds__(256) void k_fuse(
    const ushort* __restrict__ h,
    const float* __restrict__ gsum, const float* __restrict__ gsq,
    const float* __restrict__ gamma, const float* __restrict__ beta,
    const float* __restrict__ wc, const float* __restrict__ ow_g,
    const float* __restrict__ ob_g, float* __restrict__ out)
{
    __shared__ ushort Hh[32 * 256];   // 16KB
    __shared__ ushort Hl[32 * 256];   // 16KB
    __shared__ float  us[64 * 68];    // 17KB
    __shared__ float  ows[64];
    __shared__ float  abs_[512];      // scale | shift

    const int t   = threadIdx.x;
    const int wid = t >> 6;
    const int l   = t & 63;
    const int g   = l >> 4;           // 0..3
    const int lc  = l & 15;

    {
        float mean = gsum[t] * INV_B;
        float var  = gsq[t] * INV_B - mean * mean;
        float rstd = rsqrtf(var + 1e-5f);
        float a = gamma[t] * rstd;
        abs_[t]       = a;
        abs_[256 + t] = beta[t] - mean * a;
    }
    if (t < 64) ows[t] = ow_g[t];

    short8 afh[8], afl[8];
#pragma unroll
    for (int ks = 0; ks < 8; ++ks) {
        union { ushort u16[8]; short8 v; } ph, pl;
#pragma unroll
        for (int j = 0; j < 8; ++j) {
            const int d = ks * 32 + g * 8 + j;
            float wv = wc[wid * 4096 + d * 16 + lc];
            unsigned hh = bf16_rn(wv);
            float res = wv - __uint_as_float(hh << 16);
            ph.u16[j] = (ushort)hh;
            pl.u16[j] = (ushort)bf16_rn(res);
        }
        afh[ks] = ph.v;
        afl[ks] = pl.v;
    }
    __syncthreads();   // abs_ ready

    const int c8 = (t & 31) * 8;      // staging column group
    float a_[8], cj[8];
    {
        float4 x0 = *(const float4*)(abs_ + c8);
        float4 x1 = *(const float4*)(abs_ + c8 + 4);
        float4 y0 = *(const float4*)(abs_ + 256 + c8);
        float4 y1 = *(const float4*)(abs_ + 256 + c8 + 4);
        a_[0]=x0.x; a_[1]=x0.y; a_[2]=x0.z; a_[3]=x0.w;
        a_[4]=x1.x; a_[5]=x1.y; a_[6]=x1.z; a_[7]=x1.w;
        cj[0]=y0.x; cj[1]=y0.y; cj[2]=y0.z; cj[3]=y0.w;
        cj[4]=y1.x; cj[5]=y1.y; cj[6]=y1.z; cj[7]=y1.w;
    }

    const int rowBase = (int)blockIdx.x * 64;

#pragma unroll
    for (int sub = 0; sub < 2; ++sub) {
        const int row0 = rowBase + sub * 32;

        __syncthreads();

#pragma unroll
        for (int it = 0; it < 4; ++it) {
            const int r = it * 8 + (t >> 5);          // 0..31
            const ushort* hp = h + (size_t)(row0 + r) * 256 + c8;
            short8 hraw = *(const short8*)hp;         // 16B of bf16
            float hv[8];
#pragma unroll
            for (int j = 0; j < 8; ++j) {
                unsigned ub = (unsigned)(ushort)hraw[j];
                hv[j] = __uint_as_float(ub << 16);
                hv[j] = fmaxf(fmaf(hv[j], a_[j], cj[j]), 0.f);
            }
            uint4 hi, lo;
            split8(hv, hi, lo);
            const int slot = (t & 31) ^ (r & 7);
            *(uint4*)&Hh[r * 256 + slot * 8] = hi;
            *(uint4*)&Hl[r * 256 + slot * 8] = lo;
        }
        __syncthreads();

        f32x4 acc0 = (f32x4){0.f,0.f,0.f,0.f};
        f32x4 acc1 = (f32x4){0.f,0.f,0.f,0.f};
#pragma unroll
        for (int ks = 0; ks < 8; ++ks) {
            {
                const int row  = lc;                   // nt = 0
                const int slot = (ks * 4 + g) ^ (row & 7);
                short8 bh = *(const short8*)&Hh[row * 256 + slot * 8];
                short8 bl = *(const short8*)&Hl[row * 256 + slot * 8];
                acc0 = __builtin_amdgcn_mfma_f32_16x16x32_bf16(afh[ks], bh, acc0, 0,0,0);
                acc0 = __builtin_amdgcn_mfma_f32_16x16x32_bf16(afh[ks], bl, acc0, 0,0,0);
                acc0 = __builtin_amdgcn_mfma_f32_16x16x32_bf16(afl[ks], bh, acc0, 0,0,0);
            }
            {
                const int row  = 16 + lc;              // nt = 1
                const int slot = (ks * 4 + g) ^ (row & 7);
                short8 bh = *(const short8*)&Hh[row * 256 + slot * 8];
                short8 bl = *(const short8*)&Hl[row * 256 + slot * 8];
                acc1 = __builtin_amdgcn_mfma_f32_16x16x32_bf16(afh[ks], bh, acc1, 0,0,0);
                acc1 = __builtin_amdgcn_mfma_f32_16x16x32_bf16(afh[ks], bl, acc1, 0,0,0);
                acc1 = __builtin_amdgcn_mfma_f32_16x16x32_bf16(afl[ks], bh, acc1, 0,0,0);
            }
        }
        {
            const int r0 = sub * 32 + lc;
            *(float4*)&us[r0 * 68 + wid * 16 + g * 4] =
                make_float4(acc0[0], acc0[1], acc0[2], acc0[3]);
            *(float4*)&us[(r0 + 16) * 68 + wid * 16 + g * 4] =
                make_float4(acc1[0], acc1[1], acc1[2], acc1[3]);
        }
    }
    __syncthreads();

    const int row_l = wid * 16 + lc;
    float u[16];
#pragma unroll
    for (int q = 0; q < 4; ++q) {
        float4 v4 = *(const float4*)&us[row_l * 68 + g * 16 + q * 4];
        u[q*4+0] = v4.x; u[q*4+1] = v4.y; u[q*4+2] = v4.z; u[q*4+3] = v4.w;
    }

    float n2 = 0.f;
#pragma unroll
    for (int o = 0; o < 16; ++o) n2 = fmaf(u[o], u[o], n2);
    const float nrm = sqrtf(n2);
    const float sc  = nrm / ((1.f + n2) * (nrm + 1e-8f));  // u_hat = sc*u
    const float nh2 = sc * sc * n2;
    const float nh  = sc * nrm;

    float tk[4];
#pragma unroll
    for (int k = 0; k < 4; ++k) {
        float s = 0.f;
#pragma unroll
        for (int q = 0; q < 4; ++q) {
            float4 w4 = *(const float4*)&ows[k * 16 + q * 4];
            s = fmaf(u[q*4+0], w4.x, s);
            s = fmaf(u[q*4+1], w4.y, s);
            s = fmaf(u[q*4+2], w4.z, s);
            s = fmaf(u[q*4+3], w4.w, s);
        }
        tk[k] = s;
    }

    float b = 0.f, alc = 0.f;
#pragma unroll
    for (int it3 = 0; it3 < 3; ++it3) {
        float bmax = fmaxf(b, __shfl_xor(b, 16));
        bmax = fmaxf(bmax, __shfl_xor(bmax, 32));
        float eb = __expf(b - bmax);
        float es = eb + __shfl_xor(eb, 16);
        es += __shfl_xor(es, 32);
        float c = eb / es;
        float ns  = c * nh;
        float ns2 = c * c * nh2;
        float av  = ns / ((1.f + ns2) * (ns + 1e-8f));
        alc = av * c;
        if (it3 < 2) b += alc * nh2;
    }

    const float vs = alc * sc;
    float p0 = fmaf(vs, tk[0], ob_g[0]);
    float p1 = fmaf(vs, tk[1], ob_g[1]);
    float p2 = fmaf(vs, tk[2], ob_g[2]);
    float p3 = fmaf(vs, tk[3], ob_g[3]);
    float mx = fmaxf(fmaxf(p0, p1), fmaxf(p2, p3));
    float e0 = __expf(p0 - mx), e1 = __expf(p1 - mx);
    float e2 = __expf(p2 - mx), e3 = __expf(p3 - mx);
    float inv = 1.f / (e0 + e1 + e2 + e3);
    *(float4*)&out[(size_t)(rowBase + row_l) * 16 + g * 4] =
        make_float4(e0 * inv, e1 * inv, e2 * inv, e3 * inv);
}

// ---------------------------------------------------------------------------
extern "C" void kernel_launch(void* const* d_in, const int* in_sizes, int n_in,
                              void* d_out, int out_size, void* d_ws, size_t ws_size,
                              hipStream_t stream)
{
    const float* x     = (const float*)d_in[0];
    const float* fc_w  = (const float*)d_in[1];
    const float* fc_b  = (const float*)d_in[2];
    const float* gamma = (const float*)d_in[3];
    const float* beta  = (const float*)d_in[4];
    const float* wc    = (const float*)d_in[5];
    const float* ow    = (const float*)d_in[6];
    const float* ob    = (const float*)d_in[7];
    float* out = (float*)d_out;

    float*  gsum = (float*)d_ws;                  // [256]
    float*  gsq  = gsum + 256;                    // [256]
    ushort* h    = (ushort*)((char*)d_ws + 4096); // [131072*256] bf16 = 67MB

    // w-split planes live in d_out's first 256KB: written by k_prep, read by
    // k_gemm (L2-resident), then fully overwritten by k_fuse's output (8MB).
    ushort* wsp = (ushort*)d_out;                 // hi|lo planes, BK=32 layout

    k_prep <<<dim3(32),   dim3(256), 0, stream>>>(fc_w, wsp, gsum, gsq);
    k_gemm <<<dim3(2048), dim3(256), 0, stream>>>(x, wsp, fc_b, h, gsum, gsq);
    k_fuse <<<dim3(2048), dim3(256), 0, stream>>>(h, gsum, gsq, gamma, beta,
                                                  wc, ow, ob, out);
}